// Round 8
// baseline (4310.806 us; speedup 1.0000x reference)
//
#include <hip/hip_runtime.h>
#include <hip/hip_bf16.h>

#define TOTALROWS 262144
#define NSEG      1024
#define SEGROWS   256
#define HD        64
#define DEMB      32
#define DPRE      96
#define N1        512
#define N2        1024
#define EPSB      1e-5f

typedef short s16x8 __attribute__((ext_vector_type(8)));
typedef short s16x4 __attribute__((ext_vector_type(4)));
typedef float f32x4 __attribute__((ext_vector_type(4)));

static __device__ __forceinline__ ushort f2bf(float x) {
    union { float f; unsigned u; } v; v.f = x;
    unsigned r = v.u + 0x7FFFu + ((v.u >> 16) & 1u);   // round-to-nearest-even
    return (ushort)(r >> 16);
}

// async global->LDS, 16B per lane; LDS dest = wave-uniform base + lane*16
static __device__ __forceinline__ void gload_lds16(const void* g, void* l) {
    __builtin_amdgcn_global_load_lds(
        (const __attribute__((address_space(1))) void*)g,
        (__attribute__((address_space(3))) void*)l, 16, 0, 0);
}

// ---------------- W2 + W1 f32 -> bf16 (canonical row-major) ----------------
__global__ void convert_w_kernel(const float* __restrict__ w2, ushort* __restrict__ w2b,
                                 const float* __restrict__ w1, ushort* __restrict__ w1b) {
    int i = blockIdx.x * 256 + threadIdx.x;
    const float* src; ushort* dst; int j;
    if (i < 131072) { src = w2; dst = w2b; j = i; }
    else            { src = w1; dst = w1b; j = i - 131072; if (j >= 12288) return; }
    float4 v = ((const float4*)src)[j];
    ushort4 o;
    o.x = f2bf(v.x); o.y = f2bf(v.y); o.z = f2bf(v.z); o.w = f2bf(v.w);
    ((ushort4*)dst)[j] = o;
}

// ---------------- layer 1: EXACT round-5 version (591us best) ----------------
__global__ __launch_bounds__(512, 2) void layer1_kernel(
    const float* __restrict__ hstate, const float* __restrict__ ebpr,
    const float* __restrict__ Wsp, const ushort* __restrict__ W1b,
    const float* __restrict__ g1, const float* __restrict__ be1,
    ushort* __restrict__ h1)
{
    __shared__ __align__(16) ushort As[SEGROWS * 104];   // mlp_in [256][96] pad->104
    __shared__ __align__(16) ushort Bs[SEGROWS * 104];   // W1 tile [256][96] pad->104
    __shared__ float statsS[8][4][16];
    __shared__ float statsQ[8][4][16];

    const int seg  = blockIdx.x;
    const int ct   = blockIdx.y;
    const int tid  = threadIdx.x;
    const int lane = tid & 63, wid = tid >> 6;
    const int wr   = wid >> 2, wc = wid & 3;

    // --- A cols 32..95 = h_state: one ds_write_b128 per 8 floats ---
    {
        const float4* hs4 = (const float4*)(hstate + (size_t)seg * SEGROWS * HD);
        #pragma unroll
        for (int i = 0; i < 4; ++i) {
            int u = tid + i * 512;                 // 2048 8-float chunks
            int r = u >> 3, c8 = u & 7;
            float4 v0 = hs4[2 * u];
            float4 v1 = hs4[2 * u + 1];
            s16x8 o;
            o[0] = (short)f2bf(v0.x); o[1] = (short)f2bf(v0.y);
            o[2] = (short)f2bf(v0.z); o[3] = (short)f2bf(v0.w);
            o[4] = (short)f2bf(v1.x); o[5] = (short)f2bf(v1.y);
            o[6] = (short)f2bf(v1.z); o[7] = (short)f2bf(v1.w);
            *(s16x8*)&As[r * 104 + DEMB + c8 * 8] = o;
        }
    }
    // --- A cols 0..31 = rel_emb: one ds_write_b64 per 4 outputs ---
    {
        #pragma unroll
        for (int i = 0; i < 4; ++i) {
            int u = tid + i * 512;                 // 2048 k-quads
            int r = u >> 3, kq = u & 7;
            float4 e = ((const float4*)ebpr)[seg * SEGROWS + r];
            s16x4 o;
            #pragma unroll
            for (int t = 0; t < 4; ++t) {
                float4 w = ((const float4*)Wsp)[kq * 4 + t];
                // pos = [e0, e2, e1, e3] (transpose (0,2,1) of (2,BF))
                float val = w.x * e.x + w.y * e.z + w.z * e.y + w.w * e.w;
                o[t] = (short)f2bf(val);           // b_sp cancels through segment BN
            }
            *(s16x4*)&As[r * 104 + kq * 4] = o;
        }
    }
    // --- B tile: pre-converted W1b rows ct*256..+256 ---
    {
        const s16x8* w18 = (const s16x8*)(W1b + (size_t)ct * 256 * DPRE);
        #pragma unroll
        for (int i = 0; i < 6; ++i) {
            int u = tid + i * 512;                 // 3072 16B chunks
            int r = u / 12, c8 = u % 12;
            *(s16x8*)&Bs[r * 104 + c8 * 8] = w18[u];
        }
    }
    __syncthreads();

    f32x4 acc[8][4] = {};
    const int arow0 = wr * 128 + (lane & 15);
    const int bcol0 = wc * 64  + (lane & 15);
    const int kg    = (lane >> 4) * 8;
    #pragma unroll
    for (int ks = 0; ks < 3; ++ks) {
        s16x8 af[8], bfr[4];
        #pragma unroll
        for (int m = 0; m < 8; ++m)
            af[m] = *(const s16x8*)&As[(arow0 + m * 16) * 104 + ks * 32 + kg];
        #pragma unroll
        for (int n = 0; n < 4; ++n)
            bfr[n] = *(const s16x8*)&Bs[(bcol0 + n * 16) * 104 + ks * 32 + kg];
        #pragma unroll
        for (int m = 0; m < 8; ++m)
            #pragma unroll
            for (int n = 0; n < 4; ++n)
                acc[m][n] = __builtin_amdgcn_mfma_f32_16x16x32_bf16(af[m], bfr[n], acc[m][n], 0, 0, 0);
    }

    // --- per-column stats over the 256 segment rows ---
    float s[4], q[4];
    #pragma unroll
    for (int n = 0; n < 4; ++n) { s[n] = 0.f; q[n] = 0.f; }
    #pragma unroll
    for (int m = 0; m < 8; ++m)
        #pragma unroll
        for (int n = 0; n < 4; ++n)
            #pragma unroll
            for (int j = 0; j < 4; ++j) { float v = acc[m][n][j]; s[n] += v; q[n] += v * v; }
    #pragma unroll
    for (int n = 0; n < 4; ++n) {
        s[n] += __shfl_xor(s[n], 16); q[n] += __shfl_xor(q[n], 16);
        s[n] += __shfl_xor(s[n], 32); q[n] += __shfl_xor(q[n], 32);
    }
    if ((lane >> 4) == 0) {
        #pragma unroll
        for (int n = 0; n < 4; ++n) { statsS[wid][n][lane] = s[n]; statsQ[wid][n][lane] = q[n]; }
    }
    __syncthreads();

    const float inv256 = 1.0f / 256.0f;
    float aa[4], bb[4];
    const int c16 = lane & 15;
    #pragma unroll
    for (int n = 0; n < 4; ++n) {
        float sum = statsS[wc][n][c16] + statsS[4 + wc][n][c16];
        float sq  = statsQ[wc][n][c16] + statsQ[4 + wc][n][c16];
        float mean = sum * inv256;
        float var  = sq * inv256 - mean * mean;
        float rinv = rsqrtf(var + EPSB);
        int col = ct * 256 + wc * 64 + n * 16 + c16;
        aa[n] = g1[col] * rinv;
        bb[n] = be1[col] - mean * aa[n];
    }

    ushort* outp = h1 + (size_t)(seg * SEGROWS) * N1 + ct * 256;
    const int rbase = wr * 128 + (lane >> 4) * 4;
    #pragma unroll
    for (int m = 0; m < 8; ++m)
        #pragma unroll
        for (int j = 0; j < 4; ++j) {
            int r = rbase + m * 16 + j;
            ushort* rowp = outp + (size_t)r * N1 + wc * 64 + c16;
            #pragma unroll
            for (int n = 0; n < 4; ++n) {
                float v = acc[m][n][j] * aa[n] + bb[n];
                v = v > 0.f ? v : 0.f;
                rowp[n * 16] = f2bf(v);
            }
        }
}

// ==================== layer 2: 256x256 tile, 16 waves of 64x64, 2 blocks/CU ====================
// Round-6/7 post-mortem: occupancy was capped at 8 waves/CU by the ACCUMULATOR
// (wave tile 128x64 -> 128 f32 acc/thread -> ~256 unified regs), and narrow-N
// tiles (R4/R7) multiplied A-panel traffic 2-4x and regressed. Fix both:
// keep tile 256x256 + 4096-block grid (A-traffic of R3), but 1024 threads =
// 16 waves of 64x64 -> acc[4][4] = 64 regs/thread (~120 total). LDS: BK=32,
// 2-deep dbuf = 2x16KB(A) + 2x16KB(B) + 8KB stats = 72KB -> 2 blocks/CU
// -> 32 waves/CU, 4x round-3's TLP. m97 recipe: simple 2-phase loop, latency
// hidden by co-resident waves, not in-block pipelining.
//
// Swizzle (round-1 verified, SQ_LDS_BANK_CONFLICT=0): 64B rows = 4 chunks of
// 16B; phys_chunk = logical_chunk ^ ((row>>1)&3); inverse XOR on the global
// source chunk (global_load_lds dest stays linear, rule #21), forward XOR on
// the ds_read offset.
//
// Sync invariant (round-2 lesson): compute(t)'s ds_reads sit after a barrier
// that follows the vmcnt retiring ALL of tile t's staging loads (2/thread).
// Lead-1: step t stages t+1 (2 loads -> 4 outstanding), vmcnt(2) retires
// tile t, barrier (block-wide), compute(t), closing barrier (WAR: buf[(t+1)&1]
// old reads complete block-wide before the next step's stage).

static __device__ __forceinline__ void compute_step16(
    const ushort* lA, const ushort* lB, f32x4 (&acc)[4][4],
    int arow0, int bcol0, int swz)
{
    s16x8 af[4], bfr[4];
    #pragma unroll
    for (int m = 0; m < 4; ++m)
        af[m] = *(const s16x8*)&lA[(arow0 + m * 16) * 32 + swz];
    #pragma unroll
    for (int n = 0; n < 4; ++n)
        bfr[n] = *(const s16x8*)&lB[(bcol0 + n * 16) * 32 + swz];
    __builtin_amdgcn_s_setprio(1);
    #pragma unroll
    for (int m = 0; m < 4; ++m)
        #pragma unroll
        for (int n = 0; n < 4; ++n)
            acc[m][n] = __builtin_amdgcn_mfma_f32_16x16x32_bf16(af[m], bfr[n], acc[m][n], 0, 0, 0);
    __builtin_amdgcn_s_setprio(0);
}

__global__ __launch_bounds__(1024, 8) void layer2_kernel(
    const ushort* __restrict__ h1, const ushort* __restrict__ W2b,
    const float* __restrict__ g2, const float* __restrict__ be2,
    float* __restrict__ out)
{
    __shared__ __align__(16) ushort As[2][SEGROWS * 32];  // 2 x 16 KiB
    __shared__ __align__(16) ushort Bs[2][256 * 32];      // 2 x 16 KiB
    __shared__ float statsS[16][4][16];
    __shared__ float statsQ[16][4][16];

    // bijective XCD swizzle (nwg=4096 % 8 == 0): 4 ct-siblings of a segment on
    // one XCD -> h1 panel (256KB) L2-hits 3 of 4 times.
    const int b   = blockIdx.x;
    const int wg  = (b & 7) * 512 + (b >> 3);
    const int seg = wg >> 2;
    const int ct  = wg & 3;

    const int tid  = threadIdx.x;
    const int lane = tid & 63, wid = tid >> 6;    // wid 0..15
    const int wr   = wid >> 2, wc = wid & 3;      // 4x4 wave grid, 64x64 tiles

    const char* srcA = (const char*)(h1  + (size_t)seg * SEGROWS * N1);
    const char* srcB = (const char*)(W2b + (size_t)ct  * 256    * N1);

    f32x4 acc[4][4] = {};
    const int arow0 = wr * 64 + (lane & 15);      // 0..255
    const int bcol0 = wc * 64 + (lane & 15);      // 0..255
    const int swz   = (((lane >> 4) ^ ((lane >> 1) & 3)) << 3);
    // staging: 1024 threads, 1 load each per matrix per tile.
    // dest row = wid*16 + (lane>>2), phys chunk = lane&3 -> linear wid*1024 + lane*16.
    const int cl    = (((lane & 3) ^ ((lane >> 3) & 3)) << 4); // inverse-swz src chunk
    const size_t grow = (size_t)(wid * 16 + (lane >> 2)) * 1024;

#define STAGE(T, BUF) do {                                                       \
        gload_lds16(srcA + grow + (size_t)(T) * 64 + cl, (char*)As[BUF] + wid * 1024); \
        gload_lds16(srcB + grow + (size_t)(T) * 64 + cl, (char*)Bs[BUF] + wid * 1024); \
    } while (0)

    STAGE(0, 0);                                   // 2 loads in flight

#define L2_STEP(T, VW)                                                           \
    {                                                                            \
        if ((T) + 1 < 16) STAGE((T) + 1, ((T) + 1) & 1);                         \
        asm volatile("s_waitcnt vmcnt(" #VW ")" ::: "memory");                   \
        __builtin_amdgcn_s_barrier();                                            \
        compute_step16(As[(T)&1], Bs[(T)&1], acc, arow0, bcol0, swz);            \
        asm volatile("s_barrier" ::: "memory");                                  \
    }

    L2_STEP(0, 2)   L2_STEP(1, 2)   L2_STEP(2, 2)   L2_STEP(3, 2)
    L2_STEP(4, 2)   L2_STEP(5, 2)   L2_STEP(6, 2)   L2_STEP(7, 2)
    L2_STEP(8, 2)   L2_STEP(9, 2)   L2_STEP(10, 2)  L2_STEP(11, 2)
    L2_STEP(12, 2)  L2_STEP(13, 2)  L2_STEP(14, 2)  L2_STEP(15, 0)
#undef L2_STEP
#undef STAGE

    // --- per-column stats: each wave covers 64 rows; combine the 4 wr-waves ---
    float s[4], q[4];
    #pragma unroll
    for (int n = 0; n < 4; ++n) { s[n] = 0.f; q[n] = 0.f; }
    #pragma unroll
    for (int m = 0; m < 4; ++m)
        #pragma unroll
        for (int n = 0; n < 4; ++n)
            #pragma unroll
            for (int j = 0; j < 4; ++j) { float v = acc[m][n][j]; s[n] += v; q[n] += v * v; }
    #pragma unroll
    for (int n = 0; n < 4; ++n) {
        s[n] += __shfl_xor(s[n], 16); q[n] += __shfl_xor(q[n], 16);
        s[n] += __shfl_xor(s[n], 32); q[n] += __shfl_xor(q[n], 32);
    }
    if ((lane >> 4) == 0) {
        #pragma unroll
        for (int n = 0; n < 4; ++n) { statsS[wid][n][lane] = s[n]; statsQ[wid][n][lane] = q[n]; }
    }
    __syncthreads();

    const float inv256 = 1.0f / 256.0f;
    float aa[4], bb[4];
    const int c16 = lane & 15;
    #pragma unroll
    for (int n = 0; n < 4; ++n) {
        // wid = 4*wr + wc: sum over wr = 0..3 for this wave's wc
        float sum = statsS[wc][n][c16] + statsS[4 + wc][n][c16]
                  + statsS[8 + wc][n][c16] + statsS[12 + wc][n][c16];
        float sq  = statsQ[wc][n][c16] + statsQ[4 + wc][n][c16]
                  + statsQ[8 + wc][n][c16] + statsQ[12 + wc][n][c16];
        float mean = sum * inv256;
        float var  = sq * inv256 - mean * mean;
        float rinv = rsqrtf(var + EPSB);
        int col = ct * 256 + wc * 64 + n * 16 + c16;
        aa[n] = g2[col] * rinv;
        bb[n] = be2[col] - mean * aa[n];
    }

    float* outp = out + (size_t)(seg * SEGROWS) * N2 + ct * 256;
    const int rbase = wr * 64 + (lane >> 4) * 4;
    #pragma unroll
    for (int m = 0; m < 4; ++m)
        #pragma unroll
        for (int j = 0; j < 4; ++j) {
            int r = rbase + m * 16 + j;
            float* rowp = outp + (size_t)r * N2 + wc * 64 + c16;
            #pragma unroll
            for (int n = 0; n < 4; ++n) {
                float v = acc[m][n][j] * aa[n] + bb[n];
                v = v > 0.f ? v : 0.f;
                rowp[n * 16] = v;
            }
        }
}

extern "C" void kernel_launch(void* const* d_in, const int* in_sizes, int n_in,
                              void* d_out, int out_size, void* d_ws, size_t ws_size,
                              hipStream_t stream) {
    const float* hstate = (const float*)d_in[0];
    const float* ebpr   = (const float*)d_in[1];
    const float* Wsp    = (const float*)d_in[2];
    // d_in[3] = b_sp  : cancels through segment BN (exact)
    const float* W1     = (const float*)d_in[4];
    // d_in[5] = b1    : cancels through segment BN (exact)
    const float* g1     = (const float*)d_in[6];
    const float* be1    = (const float*)d_in[7];
    const float* W2     = (const float*)d_in[8];
    // d_in[9] = b2    : cancels through segment BN (exact)
    const float* g2     = (const float*)d_in[10];
    const float* be2    = (const float*)d_in[11];
    float* outp         = (float*)d_out;

    ushort* h1  = (ushort*)d_ws;                          // 262144 x 512 bf16 = 256 MiB
    ushort* W2b = h1 + (size_t)TOTALROWS * N1;            // 1024 x 512 bf16 = 1 MiB
    ushort* W1b = W2b + (size_t)N2 * N1;                  // 512 x 96 bf16

    convert_w_kernel<<<dim3(560), dim3(256), 0, stream>>>(W2, W2b, W1, W1b);
    layer1_kernel<<<dim3(NSEG, 2), dim3(512), 0, stream>>>(hstate, ebpr, Wsp, W1b, g1, be1, h1);
    layer2_kernel<<<dim3(4096), dim3(1024), 0, stream>>>(h1, W2b, g2, be2, outp);
}

// Round 9
// 652.256 us; speedup vs baseline: 6.6091x; 6.6091x over previous
//
#include <hip/hip_runtime.h>
#include <hip/hip_bf16.h>

#define TOTALROWS 262144
#define NSEG      1024
#define SEGROWS   256
#define HD        64
#define DEMB      32
#define DPRE      96
#define N1        512
#define N2        1024
#define EPSB      1e-5f

typedef short s16x8 __attribute__((ext_vector_type(8)));
typedef short s16x4 __attribute__((ext_vector_type(4)));
typedef float f32x4 __attribute__((ext_vector_type(4)));

static __device__ __forceinline__ ushort f2bf(float x) {
    union { float f; unsigned u; } v; v.f = x;
    unsigned r = v.u + 0x7FFFu + ((v.u >> 16) & 1u);   // round-to-nearest-even
    return (ushort)(r >> 16);
}

// async global->LDS, 16B per lane; LDS dest = wave-uniform base + lane*16
static __device__ __forceinline__ void gload_lds16(const void* g, void* l) {
    __builtin_amdgcn_global_load_lds(
        (const __attribute__((address_space(1))) void*)g,
        (__attribute__((address_space(3))) void*)l, 16, 0, 0);
}

// ---------------- W2 + W1 f32 -> bf16 (canonical row-major) ----------------
__global__ void convert_w_kernel(const float* __restrict__ w2, ushort* __restrict__ w2b,
                                 const float* __restrict__ w1, ushort* __restrict__ w1b) {
    int i = blockIdx.x * 256 + threadIdx.x;
    const float* src; ushort* dst; int j;
    if (i < 131072) { src = w2; dst = w2b; j = i; }
    else            { src = w1; dst = w1b; j = i - 131072; if (j >= 12288) return; }
    float4 v = ((const float4*)src)[j];
    ushort4 o;
    o.x = f2bf(v.x); o.y = f2bf(v.y); o.z = f2bf(v.z); o.w = f2bf(v.w);
    ((ushort4*)dst)[j] = o;
}

// ---------------- layer 1: EXACT round-5 version (591us best) ----------------
__global__ __launch_bounds__(512, 2) void layer1_kernel(
    const float* __restrict__ hstate, const float* __restrict__ ebpr,
    const float* __restrict__ Wsp, const ushort* __restrict__ W1b,
    const float* __restrict__ g1, const float* __restrict__ be1,
    ushort* __restrict__ h1)
{
    __shared__ __align__(16) ushort As[SEGROWS * 104];   // mlp_in [256][96] pad->104
    __shared__ __align__(16) ushort Bs[SEGROWS * 104];   // W1 tile [256][96] pad->104
    __shared__ float statsS[8][4][16];
    __shared__ float statsQ[8][4][16];

    const int seg  = blockIdx.x;
    const int ct   = blockIdx.y;
    const int tid  = threadIdx.x;
    const int lane = tid & 63, wid = tid >> 6;
    const int wr   = wid >> 2, wc = wid & 3;

    // --- A cols 32..95 = h_state: one ds_write_b128 per 8 floats ---
    {
        const float4* hs4 = (const float4*)(hstate + (size_t)seg * SEGROWS * HD);
        #pragma unroll
        for (int i = 0; i < 4; ++i) {
            int u = tid + i * 512;                 // 2048 8-float chunks
            int r = u >> 3, c8 = u & 7;
            float4 v0 = hs4[2 * u];
            float4 v1 = hs4[2 * u + 1];
            s16x8 o;
            o[0] = (short)f2bf(v0.x); o[1] = (short)f2bf(v0.y);
            o[2] = (short)f2bf(v0.z); o[3] = (short)f2bf(v0.w);
            o[4] = (short)f2bf(v1.x); o[5] = (short)f2bf(v1.y);
            o[6] = (short)f2bf(v1.z); o[7] = (short)f2bf(v1.w);
            *(s16x8*)&As[r * 104 + DEMB + c8 * 8] = o;
        }
    }
    // --- A cols 0..31 = rel_emb: one ds_write_b64 per 4 outputs ---
    {
        #pragma unroll
        for (int i = 0; i < 4; ++i) {
            int u = tid + i * 512;                 // 2048 k-quads
            int r = u >> 3, kq = u & 7;
            float4 e = ((const float4*)ebpr)[seg * SEGROWS + r];
            s16x4 o;
            #pragma unroll
            for (int t = 0; t < 4; ++t) {
                float4 w = ((const float4*)Wsp)[kq * 4 + t];
                // pos = [e0, e2, e1, e3] (transpose (0,2,1) of (2,BF))
                float val = w.x * e.x + w.y * e.z + w.z * e.y + w.w * e.w;
                o[t] = (short)f2bf(val);           // b_sp cancels through segment BN
            }
            *(s16x4*)&As[r * 104 + kq * 4] = o;
        }
    }
    // --- B tile: pre-converted W1b rows ct*256..+256 ---
    {
        const s16x8* w18 = (const s16x8*)(W1b + (size_t)ct * 256 * DPRE);
        #pragma unroll
        for (int i = 0; i < 6; ++i) {
            int u = tid + i * 512;                 // 3072 16B chunks
            int r = u / 12, c8 = u % 12;
            *(s16x8*)&Bs[r * 104 + c8 * 8] = w18[u];
        }
    }
    __syncthreads();

    f32x4 acc[8][4] = {};
    const int arow0 = wr * 128 + (lane & 15);
    const int bcol0 = wc * 64  + (lane & 15);
    const int kg    = (lane >> 4) * 8;
    #pragma unroll
    for (int ks = 0; ks < 3; ++ks) {
        s16x8 af[8], bfr[4];
        #pragma unroll
        for (int m = 0; m < 8; ++m)
            af[m] = *(const s16x8*)&As[(arow0 + m * 16) * 104 + ks * 32 + kg];
        #pragma unroll
        for (int n = 0; n < 4; ++n)
            bfr[n] = *(const s16x8*)&Bs[(bcol0 + n * 16) * 104 + ks * 32 + kg];
        #pragma unroll
        for (int m = 0; m < 8; ++m)
            #pragma unroll
            for (int n = 0; n < 4; ++n)
                acc[m][n] = __builtin_amdgcn_mfma_f32_16x16x32_bf16(af[m], bfr[n], acc[m][n], 0, 0, 0);
    }

    // --- per-column stats over the 256 segment rows ---
    float s[4], q[4];
    #pragma unroll
    for (int n = 0; n < 4; ++n) { s[n] = 0.f; q[n] = 0.f; }
    #pragma unroll
    for (int m = 0; m < 8; ++m)
        #pragma unroll
        for (int n = 0; n < 4; ++n)
            #pragma unroll
            for (int j = 0; j < 4; ++j) { float v = acc[m][n][j]; s[n] += v; q[n] += v * v; }
    #pragma unroll
    for (int n = 0; n < 4; ++n) {
        s[n] += __shfl_xor(s[n], 16); q[n] += __shfl_xor(q[n], 16);
        s[n] += __shfl_xor(s[n], 32); q[n] += __shfl_xor(q[n], 32);
    }
    if ((lane >> 4) == 0) {
        #pragma unroll
        for (int n = 0; n < 4; ++n) { statsS[wid][n][lane] = s[n]; statsQ[wid][n][lane] = q[n]; }
    }
    __syncthreads();

    const float inv256 = 1.0f / 256.0f;
    float aa[4], bb[4];
    const int c16 = lane & 15;
    #pragma unroll
    for (int n = 0; n < 4; ++n) {
        float sum = statsS[wc][n][c16] + statsS[4 + wc][n][c16];
        float sq  = statsQ[wc][n][c16] + statsQ[4 + wc][n][c16];
        float mean = sum * inv256;
        float var  = sq * inv256 - mean * mean;
        float rinv = rsqrtf(var + EPSB);
        int col = ct * 256 + wc * 64 + n * 16 + c16;
        aa[n] = g1[col] * rinv;
        bb[n] = be1[col] - mean * aa[n];
    }

    ushort* outp = h1 + (size_t)(seg * SEGROWS) * N1 + ct * 256;
    const int rbase = wr * 128 + (lane >> 4) * 4;
    #pragma unroll
    for (int m = 0; m < 8; ++m)
        #pragma unroll
        for (int j = 0; j < 4; ++j) {
            int r = rbase + m * 16 + j;
            ushort* rowp = outp + (size_t)r * N1 + wc * 64 + c16;
            #pragma unroll
            for (int n = 0; n < 4; ++n) {
                float v = acc[m][n][j] * aa[n] + bb[n];
                v = v > 0.f ? v : 0.f;
                rowp[n * 16] = f2bf(v);
            }
        }
}

// ==================== layer 2: 256x128, 8 waves of 64x64, 16 waves/CU, NO SPILL ====================
// Round-8 lesson (measured): __launch_bounds__(1024,8) demanded 8 waves/SIMD
// -> VGPR cap 64 -> compiler allocated 32 and SPILLED acc to scratch
// (WRITE_SIZE 13.3GB vs 1.07 ideal). The occupancy ladder (m69) steps at
// VGPR {64,128,256} -> {8,4,2} waves/SIMD. Wave tile 64x64 (acc = 64 VGPR,
// ~116 total) fits the 128 step: 4 waves/SIMD = 16 waves/CU, the max TLP
// without spilling.
//
// Geometry: tile 256(M) x 128(N), 512 threads = 8 waves (4M x 2N of 64x64).
// __launch_bounds__(512,4) -> cap 128 VGPR -> 2 blocks/CU (LDS 52KB also
// allows 2). Cross-block overlap hides staging latency (m97 mechanism) --
// unlike R3/R6's single 8-wave barrier-locked block (measured 20% occupancy,
// MfmaUtil 5.5%).
//
// BK=32 (16 K-steps), 2-deep dbuf, lead-1, counted vmcnt(3) (3 staging
// loads/thread/tile: A 2 + B 1). Swizzle pair verified in R1 (conflicts=0):
// phys_chunk = logical ^ ((row>>1)&3); inverse XOR on global source chunk
// (gload_lds dest stays linear, rule #21), forward XOR on ds_read offset.
//
// Sync invariant (R2 lesson): compute(t)'s ds_reads come after a barrier that
// follows vmcnt retiring ALL of tile t's loads. Steady state: stage(t+1)
// [3 loads, 6 outstanding] -> vmcnt(3) retires tile t -> barrier -> compute(t)
// -> barrier (WAR: buf[(t+1)&1]'s prior reads completed block-wide).

static __device__ __forceinline__ void stage_tile(
    const char* gA, const char* gB, char* lA, char* lB,
    int t, int wid, int lane)
{
    const int rsub = lane >> 2;                               // 16 rows per group
    const int cl   = (((lane & 3) ^ ((lane >> 3) & 3)) << 4); // inverse-swz chunk
    #pragma unroll
    for (int i = 0; i < 2; ++i) {
        int g = i * 8 + wid;                                  // 0..15 -> 256 A rows
        gload_lds16(gA + (size_t)(g * 16 + rsub) * 1024 + (size_t)t * 64 + cl,
                    lA + g * 1024);
    }
    // B: 128 rows, group = wid (0..7)
    gload_lds16(gB + (size_t)(wid * 16 + rsub) * 1024 + (size_t)t * 64 + cl,
                lB + wid * 1024);
}

static __device__ __forceinline__ void compute_step(
    const ushort* lA, const ushort* lB, f32x4 (&acc)[4][4],
    int arow0, int bcol0, int swz)
{
    s16x8 af[4], bfr[4];
    #pragma unroll
    for (int m = 0; m < 4; ++m)
        af[m] = *(const s16x8*)&lA[(arow0 + m * 16) * 32 + swz];
    #pragma unroll
    for (int n = 0; n < 4; ++n)
        bfr[n] = *(const s16x8*)&lB[(bcol0 + n * 16) * 32 + swz];
    __builtin_amdgcn_s_setprio(1);
    #pragma unroll
    for (int m = 0; m < 4; ++m)
        #pragma unroll
        for (int n = 0; n < 4; ++n)
            acc[m][n] = __builtin_amdgcn_mfma_f32_16x16x32_bf16(af[m], bfr[n], acc[m][n], 0, 0, 0);
    __builtin_amdgcn_s_setprio(0);
}

__global__ __launch_bounds__(512, 4) void layer2_kernel(
    const ushort* __restrict__ h1, const ushort* __restrict__ W2b,
    const float* __restrict__ g2, const float* __restrict__ be2,
    float* __restrict__ out)
{
    __shared__ __align__(16) ushort As[2][SEGROWS * 32];  // 2 x 16 KiB
    __shared__ __align__(16) ushort Bs[2][128 * 32];      // 2 x 8 KiB
    __shared__ float statsS[8][4][16];
    __shared__ float statsQ[8][4][16];

    // bijective XCD swizzle (nwg=8192 % 8 == 0): the 8 ct-siblings of a segment
    // run on one XCD -> h1 A-panel (256KB) L2-hits 7 of 8 times.
    const int b   = blockIdx.x;
    const int wg  = (b & 7) * 1024 + (b >> 3);
    const int seg = wg >> 3;
    const int ct  = wg & 7;

    const int tid  = threadIdx.x;
    const int lane = tid & 63, wid = tid >> 6;    // wid 0..7
    const int wr   = wid >> 1, wc = wid & 1;      // 4M x 2N wave grid

    const char* srcA = (const char*)(h1  + (size_t)seg * SEGROWS * N1);
    const char* srcB = (const char*)(W2b + (size_t)ct  * 128    * N1);

    f32x4 acc[4][4] = {};
    const int arow0 = wr * 64 + (lane & 15);      // 0..255
    const int bcol0 = wc * 64 + (lane & 15);      // 0..127
    const int swz   = (((lane >> 4) ^ ((lane >> 1) & 3)) << 3);

    // prologue: tile 0 staged (3 loads/thread in flight)
    stage_tile(srcA, srcB, (char*)As[0], (char*)Bs[0], 0, wid, lane);

#define L2_STEP(T, VW)                                                           \
    {                                                                            \
        if ((T) + 1 < 16)                                                        \
            stage_tile(srcA, srcB, (char*)As[((T)+1)&1], (char*)Bs[((T)+1)&1],   \
                       (T)+1, wid, lane);                                        \
        asm volatile("s_waitcnt vmcnt(" #VW ")" ::: "memory");                   \
        __builtin_amdgcn_s_barrier();                                            \
        compute_step(As[(T)&1], Bs[(T)&1], acc, arow0, bcol0, swz);              \
        __builtin_amdgcn_sched_barrier(0);                                       \
        asm volatile("s_barrier" ::: "memory");                                  \
    }

    L2_STEP(0, 3)   L2_STEP(1, 3)   L2_STEP(2, 3)   L2_STEP(3, 3)
    L2_STEP(4, 3)   L2_STEP(5, 3)   L2_STEP(6, 3)   L2_STEP(7, 3)
    L2_STEP(8, 3)   L2_STEP(9, 3)   L2_STEP(10, 3)  L2_STEP(11, 3)
    L2_STEP(12, 3)  L2_STEP(13, 3)  L2_STEP(14, 3)  L2_STEP(15, 0)
#undef L2_STEP

    // --- per-column stats: combine the 4 wr-waves of each column block ---
    float s[4], q[4];
    #pragma unroll
    for (int n = 0; n < 4; ++n) { s[n] = 0.f; q[n] = 0.f; }
    #pragma unroll
    for (int m = 0; m < 4; ++m)
        #pragma unroll
        for (int n = 0; n < 4; ++n)
            #pragma unroll
            for (int j = 0; j < 4; ++j) { float v = acc[m][n][j]; s[n] += v; q[n] += v * v; }
    #pragma unroll
    for (int n = 0; n < 4; ++n) {
        s[n] += __shfl_xor(s[n], 16); q[n] += __shfl_xor(q[n], 16);
        s[n] += __shfl_xor(s[n], 32); q[n] += __shfl_xor(q[n], 32);
    }
    if ((lane >> 4) == 0) {
        #pragma unroll
        for (int n = 0; n < 4; ++n) { statsS[wid][n][lane] = s[n]; statsQ[wid][n][lane] = q[n]; }
    }
    __syncthreads();

    const float inv256 = 1.0f / 256.0f;
    float aa[4], bb[4];
    const int c16 = lane & 15;
    #pragma unroll
    for (int n = 0; n < 4; ++n) {
        // wid = wr*2 + wc: sum over wr = 0..3 for this wave's wc
        float sum = statsS[wc][n][c16] + statsS[2 + wc][n][c16]
                  + statsS[4 + wc][n][c16] + statsS[6 + wc][n][c16];
        float sq  = statsQ[wc][n][c16] + statsQ[2 + wc][n][c16]
                  + statsQ[4 + wc][n][c16] + statsQ[6 + wc][n][c16];
        float mean = sum * inv256;
        float var  = sq * inv256 - mean * mean;
        float rinv = rsqrtf(var + EPSB);
        int col = ct * 128 + wc * 64 + n * 16 + c16;
        aa[n] = g2[col] * rinv;
        bb[n] = be2[col] - mean * aa[n];
    }

    float* outp = out + (size_t)(seg * SEGROWS) * N2 + ct * 128;
    const int rbase = wr * 64 + (lane >> 4) * 4;
    #pragma unroll
    for (int m = 0; m < 4; ++m)
        #pragma unroll
        for (int j = 0; j < 4; ++j) {
            int r = rbase + m * 16 + j;
            float* rowp = outp + (size_t)r * N2 + wc * 64 + c16;
            #pragma unroll
            for (int n = 0; n < 4; ++n) {
                float v = acc[m][n][j] * aa[n] + bb[n];
                v = v > 0.f ? v : 0.f;
                rowp[n * 16] = v;
            }
        }
}

extern "C" void kernel_launch(void* const* d_in, const int* in_sizes, int n_in,
                              void* d_out, int out_size, void* d_ws, size_t ws_size,
                              hipStream_t stream) {
    const float* hstate = (const float*)d_in[0];
    const float* ebpr   = (const float*)d_in[1];
    const float* Wsp    = (const float*)d_in[2];
    // d_in[3] = b_sp  : cancels through segment BN (exact)
    const float* W1     = (const float*)d_in[4];
    // d_in[5] = b1    : cancels through segment BN (exact)
    const float* g1     = (const float*)d_in[6];
    const float* be1    = (const float*)d_in[7];
    const float* W2     = (const float*)d_in[8];
    // d_in[9] = b2    : cancels through segment BN (exact)
    const float* g2     = (const float*)d_in[10];
    const float* be2    = (const float*)d_in[11];
    float* outp         = (float*)d_out;

    ushort* h1  = (ushort*)d_ws;                          // 262144 x 512 bf16 = 256 MiB
    ushort* W2b = h1 + (size_t)TOTALROWS * N1;            // 1024 x 512 bf16 = 1 MiB
    ushort* W1b = W2b + (size_t)N2 * N1;                  // 512 x 96 bf16

    convert_w_kernel<<<dim3(560), dim3(256), 0, stream>>>(W2, W2b, W1, W1b);
    layer1_kernel<<<dim3(NSEG, 2), dim3(512), 0, stream>>>(hstate, ebpr, Wsp, W1b, g1, be1, h1);
    layer2_kernel<<<dim3(8192), dim3(512), 0, stream>>>(h1, W2b, g2, be2, outp);
}